// Round 9
// baseline (555.315 us; speedup 1.0000x reference)
//
#include <hip/hip_runtime.h>

#define EPS_BN 1e-4f
constexpr int BLK = 256;
constexpr int ECAPC = 1856;  // coarse k-grouped-4 cap (27*64 + pads)
constexpr int NCOPY = 8;     // stats atomic copies

// ---------- fine rulebook: row-major exact, stride 27 ----------
__global__ __launch_bounds__(64) void build_fine_k(
    const int* __restrict__ nbr, int n, int* __restrict__ cnt, int* __restrict__ ent) {
  int i = blockIdx.x * 64 + threadIdx.x;
  if (i >= n) return;
  int c = 0;
  const int* nr = nbr + (size_t)i * 27;
  int* er = ent + (size_t)i * 27;
#pragma unroll 1
  for (int k = 0; k < 27; ++k) {
    int j = nr[k];
    if (j >= 0) er[c++] = (k << 18) | j;
  }
  cnt[i] = c;
}

// ---------- coarse rulebook: k-grouped, padded to groups of 4 ----------
// entry = (r<<23)|(k<<18)|j ; pad = -1 (group tails only; first of group real)
__global__ __launch_bounds__(64) void build_subm4_k(
    const int* __restrict__ nbr, int n,
    int* __restrict__ segP, int* __restrict__ ent) {
  int T = blockIdx.x, r = threadIdx.x;
  int i = T * 64 + r;
  bool valid = i < n;
  int base = 0;
#pragma unroll 1
  for (int k = 0; k < 27; ++k) {
    int j = valid ? nbr[(size_t)i * 27 + k] : -1;
    bool act = j >= 0;
    unsigned long long mb = __ballot(act);
    int cntk = __popcll(mb);
    int pre = __popcll(mb & ((1ull << r) - 1));
    if (act) ent[(size_t)T * ECAPC + base + pre] = (r << 23) | (k << 18) | j;
    int padded = (cntk + 3) & ~3;
    if (r < padded - cntk) ent[(size_t)T * ECAPC + base + cntk + r] = -1;
    base += padded;
  }
  if (r == 0) segP[T] = base;
}

__global__ __launch_bounds__(BLK) void child_scatter_k(
    const int* __restrict__ parent, const int* __restrict__ offid, int n,
    int* __restrict__ ccnt, int* __restrict__ cent) {
  int i = blockIdx.x * BLK + threadIdx.x;
  if (i >= n) return;
  int p = parent[i];
  int slot = atomicAdd(&ccnt[p], 1);
  cent[p * 8 + slot] = i | (offid[i] << 25);
}

// ---------- Type A (R6-proven): output-stationary register-acc gather ----------
template <int CI, int CO, int MODE>
__global__ __launch_bounds__(BLK) void tconvA_k(
    const float* __restrict__ in, const int* __restrict__ ent, const int* __restrict__ cnt,
    const int* __restrict__ parent, const int* __restrict__ offid,
    const float* __restrict__ W, float* __restrict__ out, int n,
    float* __restrict__ osums) {
  constexpr int LANES = CO / 4, SLOTS = BLK / LANES, RPS = 64 / SLOTS;
  __shared__ float red[2 * CO];
  int t = threadIdx.x;
  for (int idx = t; idx < 2 * CO; idx += BLK) red[idx] = 0.f;
  __syncthreads();
  int slot = t / LANES, lane = t % LANES, g = lane * 4;
  int T = blockIdx.x;
  float ssum[4] = {0, 0, 0, 0}, ssq[4] = {0, 0, 0, 0};
#pragma unroll 1
  for (int rr = 0; rr < RPS; ++rr) {
    int row = T * 64 + slot * RPS + rr;
    bool vrow = row < n;
    float a0 = 0.f, a1 = 0.f, a2 = 0.f, a3 = 0.f;
    int ec = 0;
    if (vrow) ec = (MODE == 2) ? 1 : cnt[row];
#pragma unroll 1
    for (int e = 0; e < ec; ++e) {
      int k, j;
      if constexpr (MODE == 0) {
        int v = ent[(size_t)row * 27 + e];
        k = (v >> 18) & 31; j = v & 0x3FFFF;
      } else if constexpr (MODE == 1) {
        int v = ent[(size_t)row * 8 + e];
        k = v >> 25; j = v & 0x1FFFFFF;
      } else {
        k = offid[row]; j = parent[row];
      }
      const float* Wk = W + (size_t)k * (CI * CO) + g;
      const float* xr = in + (size_t)j * CI;
#pragma unroll
      for (int h = 0; h < CI / 32; ++h) {
        float4 xv[8];
#pragma unroll
        for (int c4 = 0; c4 < 8; ++c4)
          xv[c4] = *reinterpret_cast<const float4*>(xr + h * 32 + c4 * 4);
#pragma unroll
        for (int c4 = 0; c4 < 8; ++c4) {
          float xs[4] = {xv[c4].x, xv[c4].y, xv[c4].z, xv[c4].w};
#pragma unroll
          for (int q = 0; q < 4; ++q) {
            float4 wv = *reinterpret_cast<const float4*>(Wk + (size_t)(h * 32 + c4 * 4 + q) * CO);
            a0 = fmaf(xs[q], wv.x, a0);
            a1 = fmaf(xs[q], wv.y, a1);
            a2 = fmaf(xs[q], wv.z, a2);
            a3 = fmaf(xs[q], wv.w, a3);
          }
        }
      }
    }
    if (vrow)
      *reinterpret_cast<float4*>(out + (size_t)row * CO + g) = make_float4(a0, a1, a2, a3);
    ssum[0] += a0; ssum[1] += a1; ssum[2] += a2; ssum[3] += a3;
    ssq[0] = fmaf(a0, a0, ssq[0]); ssq[1] = fmaf(a1, a1, ssq[1]);
    ssq[2] = fmaf(a2, a2, ssq[2]); ssq[3] = fmaf(a3, a3, ssq[3]);
  }
#pragma unroll
  for (int q = 0; q < 4; ++q) {
    atomicAdd(&red[g + q], ssum[q]);
    atomicAdd(&red[CO + g + q], ssq[q]);
  }
  __syncthreads();
  int copy = blockIdx.x & (NCOPY - 1);
  if (t < 2 * CO) atomicAdd(&osums[copy * 2 * CO + t], red[t]);
}

// ---------- Type B v4: 16B-aligned LDS rows (pad 68), dual-group ILP ----------
template <int CI, int CO>   // 64, 64
__global__ __launch_bounds__(BLK) void tconvB_k(
    const float* __restrict__ in, const int* __restrict__ segP,
    const int* __restrict__ ent, int ecap,
    const float* __restrict__ sums, const float* __restrict__ gm,
    const float* __restrict__ bt, float invn,
    const float* __restrict__ W, float* __restrict__ out, int n,
    float* __restrict__ osums) {
  constexpr int AP = CO + 4;      // 68: 16B-aligned rows, bank-rotating
  constexpr int XP = CI + 4;      // 68
  constexpr int CHUNK = 128;      // pairs per staged chunk
  __shared__ float lacc[64 * AP];
  __shared__ float lx[CHUNK * XP];
  __shared__ int   lent[CHUNK];
  __shared__ float lst[2 * CI];
  int t = threadIdx.x, T = blockIdx.x;
  if (t < CI) {
    float s = 0.f, q = 0.f;
#pragma unroll
    for (int cp = 0; cp < NCOPY; ++cp) { s += sums[cp * 2 * CI + t]; q += sums[cp * 2 * CI + CI + t]; }
    float mu = s * invn, var = q * invn - mu * mu;
    float sc = gm[t] / sqrtf(var + EPS_BN);
    lst[t] = sc; lst[CI + t] = bt[t] - mu * sc;
  }
  for (int idx = t; idx < 64 * AP; idx += BLK) lacc[idx] = 0.f;
  int P = segP[T];
  const int* entT = ent + (size_t)T * ecap;
  int slot = t >> 4, g = (t & 15) * 4;
  __syncthreads();

#pragma unroll 1
  for (int c0 = 0; c0 < P; c0 += CHUNK) {
    int lim = min(P - c0, CHUNK);
    // stage entries + X rows (BN+ReLU applied once per pair here)
    if (t < CHUNK) lent[t] = (t < lim) ? entT[c0 + t] : -1;
    for (int idx = t; idx < CHUNK * 16; idx += BLK) {
      int pr = idx >> 4, cq = idx & 15;
      int ev = (pr < lim) ? entT[c0 + pr] : -1;
      float4 v = make_float4(0.f, 0.f, 0.f, 0.f);
      if (ev >= 0) {
        int j = ev & 0x3FFFF;
        float4 x = *reinterpret_cast<const float4*>(in + (size_t)j * CI + cq * 4);
        int cb = cq * 4;
        float y0 = fmaf(x.x, lst[cb + 0], lst[CI + cb + 0]);
        float y1 = fmaf(x.y, lst[cb + 1], lst[CI + cb + 1]);
        float y2 = fmaf(x.z, lst[cb + 2], lst[CI + cb + 2]);
        float y3 = fmaf(x.w, lst[cb + 3], lst[CI + cb + 3]);
        v = make_float4(y0 > 0.f ? y0 : 0.f, y1 > 0.f ? y1 : 0.f,
                        y2 > 0.f ? y2 : 0.f, y3 > 0.f ? y3 : 0.f);
      }
      *reinterpret_cast<float4*>(&lx[pr * XP + cq * 4]) = v;
    }
    __syncthreads();
    // compute: two independent 4-pair groups per slot (gr=slot, gr+16)
    {
      int pA = slot * 4;              // group A pair base
      int pB = (slot + 16) * 4;       // group B pair base
      bool hasA = pA < lim, hasB = pB < lim;
      int kA = 0, kB = 0;
      const float* WA = W; const float* WB = W;
      int rA[4], rB[4];
      float accA[4][4], accB[4][4];
      if (hasA) {
        kA = (lent[pA] >> 18) & 31;
        WA = W + (size_t)kA * (CI * CO) + g;
#pragma unroll
        for (int pp = 0; pp < 4; ++pp) {
          int ev = lent[pA + pp];
          rA[pp] = ev >= 0 ? ((ev >> 23) & 63) : -1;
          accA[pp][0] = accA[pp][1] = accA[pp][2] = accA[pp][3] = 0.f;
        }
      }
      if (hasB) {
        kB = (lent[pB] >> 18) & 31;
        WB = W + (size_t)kB * (CI * CO) + g;
#pragma unroll
        for (int pp = 0; pp < 4; ++pp) {
          int ev = lent[pB + pp];
          rB[pp] = ev >= 0 ? ((ev >> 23) & 63) : -1;
          accB[pp][0] = accB[pp][1] = accB[pp][2] = accB[pp][3] = 0.f;
        }
      }
      if (hasA) {
#pragma unroll 4
        for (int c4 = 0; c4 < CI / 4; ++c4) {
          int cb = c4 * 4;
          float4 xA[4], xB[4], wA[4], wB[4];
#pragma unroll
          for (int pp = 0; pp < 4; ++pp)
            xA[pp] = *reinterpret_cast<const float4*>(&lx[(pA + pp) * XP + cb]);
          if (hasB) {
#pragma unroll
            for (int pp = 0; pp < 4; ++pp)
              xB[pp] = *reinterpret_cast<const float4*>(&lx[(pB + pp) * XP + cb]);
          }
#pragma unroll
          for (int q = 0; q < 4; ++q)
            wA[q] = *reinterpret_cast<const float4*>(WA + (size_t)(cb + q) * CO);
          if (hasB) {
#pragma unroll
            for (int q = 0; q < 4; ++q)
              wB[q] = *reinterpret_cast<const float4*>(WB + (size_t)(cb + q) * CO);
          }
#pragma unroll
          for (int pp = 0; pp < 4; ++pp) {
            float xs[4] = {xA[pp].x, xA[pp].y, xA[pp].z, xA[pp].w};
#pragma unroll
            for (int q = 0; q < 4; ++q) {
              accA[pp][0] = fmaf(xs[q], wA[q].x, accA[pp][0]);
              accA[pp][1] = fmaf(xs[q], wA[q].y, accA[pp][1]);
              accA[pp][2] = fmaf(xs[q], wA[q].z, accA[pp][2]);
              accA[pp][3] = fmaf(xs[q], wA[q].w, accA[pp][3]);
            }
          }
          if (hasB) {
#pragma unroll
            for (int pp = 0; pp < 4; ++pp) {
              float xs[4] = {xB[pp].x, xB[pp].y, xB[pp].z, xB[pp].w};
#pragma unroll
              for (int q = 0; q < 4; ++q) {
                accB[pp][0] = fmaf(xs[q], wB[q].x, accB[pp][0]);
                accB[pp][1] = fmaf(xs[q], wB[q].y, accB[pp][1]);
                accB[pp][2] = fmaf(xs[q], wB[q].z, accB[pp][2]);
                accB[pp][3] = fmaf(xs[q], wB[q].w, accB[pp][3]);
              }
            }
          }
        }
#pragma unroll
        for (int pp = 0; pp < 4; ++pp) {
          if (rA[pp] >= 0) {
            float* ap = &lacc[rA[pp] * AP + g];
            atomicAdd(ap + 0, accA[pp][0]);
            atomicAdd(ap + 1, accA[pp][1]);
            atomicAdd(ap + 2, accA[pp][2]);
            atomicAdd(ap + 3, accA[pp][3]);
          }
        }
        if (hasB) {
#pragma unroll
          for (int pp = 0; pp < 4; ++pp) {
            if (rB[pp] >= 0) {
              float* ap = &lacc[rB[pp] * AP + g];
              atomicAdd(ap + 0, accB[pp][0]);
              atomicAdd(ap + 1, accB[pp][1]);
              atomicAdd(ap + 2, accB[pp][2]);
              atomicAdd(ap + 3, accB[pp][3]);
            }
          }
        }
      }
    }
    __syncthreads();
  }

  // epilogue: coalesced store + fused per-channel stats
  for (int idx = t; idx < 64 * (CO / 4); idx += BLK) {
    int r = idx / (CO / 4), c4 = idx - r * (CO / 4);
    int row = T * 64 + r;
    if (row < n)
      *reinterpret_cast<float4*>(out + (size_t)row * CO + c4 * 4) =
          *reinterpret_cast<const float4*>(&lacc[r * AP + c4 * 4]);
  }
  int copy = blockIdx.x & (NCOPY - 1);
  if (t < CO) {
    float s = 0.f, ss = 0.f;
#pragma unroll 4
    for (int r = 0; r < 64; ++r) {
      float x = lacc[r * AP + t];
      s += x; ss = fmaf(x, x, ss);
    }
    atomicAdd(&osums[copy * 2 * CO + t], s);
    atomicAdd(&osums[copy * 2 * CO + CO + t], ss);
  }
}

// ---------- bnact: finalize(8 copies) + relu(x*scale+shift) ----------
template <int C>
__global__ __launch_bounds__(BLK) void bnact_k(
    const float* __restrict__ in, const float* __restrict__ sums,
    const float* __restrict__ gm, const float* __restrict__ bt, float invn,
    float* __restrict__ outp, int n) {
  __shared__ float lst[2 * C];
  int t = threadIdx.x;
  if (t < C) {
    float s = 0.f, q = 0.f;
#pragma unroll
    for (int cp = 0; cp < NCOPY; ++cp) { s += sums[cp * 2 * C + t]; q += sums[cp * 2 * C + C + t]; }
    float mu = s * invn, var = q * invn - mu * mu;
    float sc = gm[t] / sqrtf(var + EPS_BN);
    lst[t] = sc; lst[C + t] = bt[t] - mu * sc;
  }
  __syncthreads();
  int total = n * (C / 4);
  const float4* in4 = reinterpret_cast<const float4*>(in);
  float4* out4 = reinterpret_cast<float4*>(outp);
  for (int idx = blockIdx.x * BLK + t; idx < total; idx += gridDim.x * BLK) {
    int cb = (idx & (C / 4 - 1)) * 4;
    float4 x = in4[idx];
    float v[4] = {x.x, x.y, x.z, x.w};
#pragma unroll
    for (int q = 0; q < 4; ++q) {
      float y = fmaf(v[q], lst[cb + q], lst[C + cb + q]);
      v[q] = y > 0.f ? y : 0.f;
    }
    out4[idx] = make_float4(v[0], v[1], v[2], v[3]);
  }
}

// ---------- bncat: concat(bn(f2), bn(u)) -> acat [N,64] ----------
__global__ __launch_bounds__(BLK) void bncat_k(
    const float* __restrict__ fa, const float* __restrict__ sA,
    const float* __restrict__ gA, const float* __restrict__ bA,
    const float* __restrict__ fb, const float* __restrict__ sB,
    const float* __restrict__ gB, const float* __restrict__ bB,
    float invn, float* __restrict__ acat, int n) {
  __shared__ float lst[128];
  int t = threadIdx.x;
  if (t < 64) {
    int half = t >> 5, c = t & 31;
    const float* ss = half ? sB : sA;
    const float* gg = half ? gB : gA;
    const float* bb = half ? bB : bA;
    float s = 0.f, q = 0.f;
#pragma unroll
    for (int cp = 0; cp < NCOPY; ++cp) { s += ss[cp * 64 + c]; q += ss[cp * 64 + 32 + c]; }
    float mu = s * invn, var = q * invn - mu * mu;
    float sc = gg[c] / sqrtf(var + EPS_BN);
    lst[half * 64 + c] = sc; lst[half * 64 + 32 + c] = bb[c] - mu * sc;
  }
  __syncthreads();
  int total = n * 16;
  for (int idx = blockIdx.x * BLK + t; idx < total; idx += gridDim.x * BLK) {
    int row = idx >> 4, c4 = idx & 15;
    int half = c4 >> 3, cc = (c4 & 7) * 4;
    const float* src = half ? fb : fa;
    float4 x = *reinterpret_cast<const float4*>(src + (size_t)row * 32 + cc);
    const float* L = lst + half * 64;
    float v[4] = {x.x, x.y, x.z, x.w};
#pragma unroll
    for (int q = 0; q < 4; ++q) {
      float y = fmaf(v[q], L[cc + q], L[32 + cc + q]);
      v[q] = y > 0.f ? y : 0.f;
    }
    *reinterpret_cast<float4*>(acat + (size_t)row * 64 + c4 * 4) = make_float4(v[0], v[1], v[2], v[3]);
  }
}

// ---------------- conv_in: [N,3] x [27,3,32] -> [N,32], fused stats ----------------
__global__ __launch_bounds__(BLK) void conv_in_k(
    const float* __restrict__ feat, const int* __restrict__ nbr,
    const float* __restrict__ W, float* __restrict__ out, int n,
    float* __restrict__ osums) {
  int i = blockIdx.x * BLK + threadIdx.x;
  bool valid = i < n;
  float acc[32];
#pragma unroll
  for (int c = 0; c < 32; ++c) acc[c] = 0.f;
#pragma unroll 1
  for (int k = 0; k < 27; ++k) {
    int j = valid ? nbr[(size_t)i * 27 + k] : -1;
    if (j < 0) continue;
    float x0 = feat[j * 3 + 0], x1 = feat[j * 3 + 1], x2 = feat[j * 3 + 2];
    const float* w0 = W + k * 96;
#pragma unroll
    for (int co = 0; co < 8; ++co) {
      float4 a = *reinterpret_cast<const float4*>(w0 + co * 4);
      float4 b = *reinterpret_cast<const float4*>(w0 + 32 + co * 4);
      float4 cc = *reinterpret_cast<const float4*>(w0 + 64 + co * 4);
      acc[4*co+0] = fmaf(x0, a.x, fmaf(x1, b.x, fmaf(x2, cc.x, acc[4*co+0])));
      acc[4*co+1] = fmaf(x0, a.y, fmaf(x1, b.y, fmaf(x2, cc.y, acc[4*co+1])));
      acc[4*co+2] = fmaf(x0, a.z, fmaf(x1, b.z, fmaf(x2, cc.z, acc[4*co+2])));
      acc[4*co+3] = fmaf(x0, a.w, fmaf(x1, b.w, fmaf(x2, cc.w, acc[4*co+3])));
    }
  }
  if (valid) {
    float* o = out + (size_t)i * 32;
#pragma unroll
    for (int co = 0; co < 8; ++co)
      *reinterpret_cast<float4*>(o + co * 4) = make_float4(acc[4*co], acc[4*co+1], acc[4*co+2], acc[4*co+3]);
  }
  __shared__ float red[2][4][32];
  int w = threadIdx.x >> 6;
#pragma unroll
  for (int c = 0; c < 32; ++c) {
    float v = acc[c], q = acc[c] * acc[c];
#pragma unroll
    for (int off = 32; off; off >>= 1) {
      v += __shfl_down(v, off);
      q += __shfl_down(q, off);
    }
    if ((threadIdx.x & 63) == 0) { red[0][w][c] = v; red[1][w][c] = q; }
  }
  __syncthreads();
  if (threadIdx.x < 64) {
    int kind = threadIdx.x >> 5, c = threadIdx.x & 31;
    float s = red[kind][0][c] + red[kind][1][c] + red[kind][2][c] + red[kind][3][c];
    atomicAdd(&osums[(blockIdx.x & (NCOPY - 1)) * 64 + kind * 32 + c], s);
  }
}

// ---------------- head: finalize(8 copies) + bn @ w_lin + b_lin -> [N,50] ----------------
__global__ __launch_bounds__(BLK) void head_k(
    const float* __restrict__ fin, const float* __restrict__ sums,
    const float* __restrict__ gm, const float* __restrict__ bt, float inv_n,
    const float* __restrict__ Wl, const float* __restrict__ bl,
    float* __restrict__ out, int n) {
  __shared__ float lw[32 * 50];
  __shared__ float lb[52];
  __shared__ float lst[64];
  int t = threadIdx.x;
  if (t < 32) {
    float s = 0.f, q = 0.f;
#pragma unroll
    for (int cp = 0; cp < NCOPY; ++cp) { s += sums[cp * 64 + t]; q += sums[cp * 64 + 32 + t]; }
    float mu = s * inv_n, var = q * inv_n - mu * mu;
    float sc = gm[t] / sqrtf(var + EPS_BN);
    lst[t] = sc; lst[32 + t] = bt[t] - mu * sc;
  }
  for (int idx = t; idx < 1600; idx += BLK) lw[idx] = Wl[idx];
  if (t < 50) lb[t] = bl[t];
  __syncthreads();
  int i = blockIdx.x * BLK + t;
  if (i >= n) return;
  float x[32];
  const float* fj = fin + (size_t)i * 32;
#pragma unroll
  for (int c4 = 0; c4 < 8; ++c4) {
    float4 v = *reinterpret_cast<const float4*>(fj + c4 * 4);
    float vs[4] = {v.x, v.y, v.z, v.w};
#pragma unroll
    for (int q = 0; q < 4; ++q) {
      int c = c4 * 4 + q;
      float y = fmaf(vs[q], lst[c], lst[32 + c]);
      x[c] = y > 0.f ? y : 0.f;
    }
  }
  float acc[50];
#pragma unroll
  for (int co = 0; co < 50; ++co) acc[co] = lb[co];
#pragma unroll 4
  for (int c = 0; c < 32; ++c) {
#pragma unroll
    for (int co = 0; co < 50; ++co) acc[co] = fmaf(x[c], lw[c * 50 + co], acc[co]);
  }
  float* o = out + (size_t)i * 50;
#pragma unroll
  for (int co = 0; co < 25; ++co)
    *reinterpret_cast<float2*>(o + co * 2) = make_float2(acc[co * 2], acc[co * 2 + 1]);
}

extern "C" void kernel_launch(void* const* d_in, const int* in_sizes, int n_in,
                              void* d_out, int out_size, void* d_ws, size_t ws_size,
                              hipStream_t stream) {
  const float* feat   = (const float*)d_in[1];
  const int*   nbrF   = (const int*)d_in[2];
  const int*   nbrC   = (const int*)d_in[3];
  const int*   parent = (const int*)d_in[4];
  const int*   offid  = (const int*)d_in[5];
  const float* w_in   = (const float*)d_in[7];
  const float* w_b1   = (const float*)d_in[8];
  const float* w_down = (const float*)d_in[9];
  const float* w_b2   = (const float*)d_in[10];
  const float* w_up   = (const float*)d_in[11];
  const float* w_b3   = (const float*)d_in[12];
  const float* g1v = (const float*)d_in[13], *b1v = (const float*)d_in[14];
  const float* gdv = (const float*)d_in[15], *bdv = (const float*)d_in[16];
  const float* g2v = (const float*)d_in[17], *b2v = (const float*)d_in[18];
  const float* guv = (const float*)d_in[19], *buv = (const float*)d_in[20];
  const float* g3v = (const float*)d_in[21], *b3v = (const float*)d_in[22];
  const float* gov = (const float*)d_in[23], *bov = (const float*)d_in[24];
  const float* w_lin = (const float*)d_in[25];
  const float* b_lin = (const float*)d_in[26];
  float* out = (float*)d_out;

  int N  = in_sizes[4];
  int NC = in_sizes[3] / 27;
  int ntF = (N + 63) / 64, ntC = (NC + 63) / 64;

  size_t szF = (size_t)N * 32;
  size_t szG = (size_t)NC * 64;
  size_t SB  = (size_t)N * 64;

  float* ws = (float*)d_ws;
  float* S1 = ws;          // f1 [N,32] -> g2c [NC,64]
  float* S2 = S1 + SB;     // a1 -> acat [N,64]
  float* S3 = S2 + SB;     // f2 [N,32] -> f3 [N,32]
  float* S4 = S3 + szF;    // a2 [N,32] -> u [N,32]
  float* S5 = S4 + szF;    // gC [NC,64] -> au [NC,64]
  float* sums1 = S5 + szG;           // 8*64
  float* sumsD = sums1 + 8 * 64;     // 8*64
  float* sums2 = sumsD + 8 * 64;     // 8*128
  float* sumsU = sums2 + 8 * 128;    // 8*128
  float* sums4 = sumsU + 8 * 128;    // 8*64
  float* sums5 = sums4 + 8 * 64;     // 8*64
  int* ccnt = (int*)(sums5 + 8 * 64);         // NC
  int* cent = ccnt + NC;                      // NC*8
  int* cntF = cent + (size_t)NC * 8;          // N
  int* entF = cntF + N;                       // N*27
  int* segPC = entF + (size_t)N * 27;         // ntC
  int* entC  = segPC + ntC;                   // ntC*ECAPC

  hipMemsetAsync(sums1, 0, (4096 + NC) * sizeof(float), stream);

  int gridN = (N + BLK - 1) / BLK;
  int agrid = 1024;
  float invN = 1.f / (float)N, invC = 1.f / (float)NC;

  // rulebooks
  build_fine_k<<<ntF, 64, 0, stream>>>(nbrF, N, cntF, entF);
  build_subm4_k<<<ntC, 64, 0, stream>>>(nbrC, NC, segPC, entC);
  child_scatter_k<<<gridN, BLK, 0, stream>>>(parent, offid, N, ccnt, cent);

  // conv_in -> f1(S1), stats -> sums1
  conv_in_k<<<gridN, BLK, 0, stream>>>(feat, nbrF, w_in, S1, N, sums1);
  bnact_k<32><<<agrid, BLK, 0, stream>>>(S1, sums1, g1v, b1v, invN, S2, N);   // a1

  // b1: a1 -> f2(S3), stats -> sumsD
  tconvA_k<32, 32, 0><<<ntF, BLK, 0, stream>>>(
      S2, entF, cntF, nullptr, nullptr, w_b1, S3, N, sumsD);
  bnact_k<32><<<agrid, BLK, 0, stream>>>(S3, sumsD, gdv, bdv, invN, S4, N);   // a2

  // down: a2 -> gC(S5), stats -> sums2
  tconvA_k<32, 64, 1><<<ntC, BLK, 0, stream>>>(
      S4, cent, ccnt, nullptr, nullptr, w_down, S5, NC, sums2);

  // b2: bn2(gC) fused at stage -> g2c(S1, f1 dead), stats -> sumsU
  tconvB_k<64, 64><<<ntC, BLK, 0, stream>>>(
      S5, segPC, entC, ECAPC, sums2, g2v, b2v, invC, w_b2, S1, NC, sumsU);
  bnact_k<64><<<agrid, BLK, 0, stream>>>(S1, sumsU, guv, buv, invC, S5, NC);  // au (gC dead)

  // up: au -> u(S4, a2 dead), stats -> sums4
  tconvA_k<64, 32, 2><<<ntF, BLK, 0, stream>>>(
      S5, nullptr, nullptr, parent, offid, w_up, S4, N, sums4);

  // bncat: (bn(f2)|bn(u)) -> acat(S2, a1 dead)
  bncat_k<<<agrid, BLK, 0, stream>>>(
      S3, sumsD, g3v, b3v, S4, sums4, g3v + 32, b3v + 32, invN, S2, N);

  // b3: acat -> f3(S3, f2 dead), stats -> sums5
  tconvA_k<64, 32, 0><<<ntF, BLK, 0, stream>>>(
      S2, entF, cntF, nullptr, nullptr, w_b3, S3, N, sums5);

  head_k<<<gridN, BLK, 0, stream>>>(S3, sums5, gov, bov, invN, w_lin, b_lin, out, N);
}